// Round 13
// baseline (219.344 us; speedup 1.0000x reference)
//
#include <hip/hip_runtime.h>
#include <math.h>

#define NEG_SLOPE 0.2f
#define EPB 16384           // edges per P1 block

typedef __attribute__((ext_vector_type(8))) short bf16x8;
typedef __attribute__((ext_vector_type(4))) float f32x4;

__device__ __forceinline__ unsigned pack_bf16x2(float a, float b) {
    unsigned ua = __float_as_uint(a);
    unsigned ub = __float_as_uint(b);
    ua += 0x7FFFu + ((ua >> 16) & 1u);     // RNE
    ub += 0x7FFFu + ((ub >> 16) & 1u);
    return (ua >> 16) | (ub & 0xFFFF0000u);
}
__device__ __forceinline__ unsigned short bf16r(float f) {
    unsigned u = __float_as_uint(f);
    u += 0x7FFFu + ((u >> 16) & 1u);
    return (unsigned short)(u >> 16);
}
__device__ __forceinline__ float bf_lo(unsigned u) { return __uint_as_float(u << 16); }
__device__ __forceinline__ float bf_hi(unsigned u) { return __uint_as_float(u & 0xFFFF0000u); }
__device__ __forceinline__ float sel4(float4 a, int h) {
    return h < 2 ? (h == 0 ? a.x : a.y) : (h == 2 ? a.z : a.w);
}

// ---- SRSRC buffer loads (32-bit voffset + SGPR soffset: near-zero VALU gathers) ----
#if defined(__has_builtin)
#if __has_builtin(__builtin_amdgcn_make_buffer_rsrc) && \
    __has_builtin(__builtin_amdgcn_raw_ptr_buffer_load_b32) && \
    __has_builtin(__builtin_amdgcn_raw_ptr_buffer_load_b64)
#define USE_BUFLD 1
#endif
#endif

#ifdef USE_BUFLD
typedef __amdgpu_buffer_rsrc_t Rsrc;
typedef __attribute__((ext_vector_type(2))) unsigned uint2v;
__device__ __forceinline__ Rsrc mkrsrc(const void* p) {
    return __builtin_amdgcn_make_buffer_rsrc((void*)p, (short)0, -1, 0x00020000);
}
__device__ __forceinline__ unsigned bufld_u32(Rsrc r, int voff) {
    return __builtin_amdgcn_raw_ptr_buffer_load_b32(r, voff, 0, 0);
}
__device__ __forceinline__ unsigned bufld_u32s(Rsrc r, int voff, int soff) {
    return __builtin_amdgcn_raw_ptr_buffer_load_b32(r, voff, soff, 0);
}
__device__ __forceinline__ float bufld_f32(Rsrc r, int voff) {
    return __uint_as_float(__builtin_amdgcn_raw_ptr_buffer_load_b32(r, voff, 0, 0));
}
__device__ __forceinline__ uint2 bufld_u64(Rsrc r, int voff) {
    uint2v v = __builtin_amdgcn_raw_ptr_buffer_load_b64(r, voff, 0, 0);
    return make_uint2(v.x, v.y);
}
#else
struct Rsrc { const char* p; };
__device__ __forceinline__ Rsrc mkrsrc(const void* p) { Rsrc r; r.p = (const char*)p; return r; }
__device__ __forceinline__ unsigned bufld_u32(Rsrc r, int voff) { return *(const unsigned*)(r.p + voff); }
__device__ __forceinline__ unsigned bufld_u32s(Rsrc r, int voff, int soff) { return *(const unsigned*)(r.p + voff + soff); }
__device__ __forceinline__ float bufld_f32(Rsrc r, int voff) { return *(const float*)(r.p + voff); }
__device__ __forceinline__ uint2 bufld_u64(Rsrc r, int voff) { return *(const uint2*)(r.p + voff); }
#endif

// LDS tile addressing: row stride 256B, XOR swizzle spreads 16 rows over 16B slots
#define SWZ(row, byteoff) ((((row) * 256) + (byteoff)) ^ (((row) & 15) << 4))

// ======== fused kernel A: wcvt (blocks 0..79) || p1_hist (blocks 80..) ========

__global__ __launch_bounds__(256) void wcvt_hist_kernel(const float* __restrict__ W1,
                                                        const float* __restrict__ W2,
                                                        unsigned short* __restrict__ W1T,
                                                        unsigned short* __restrict__ W2T,
                                                        const int* __restrict__ dst,
                                                        int E, int N, int nblk1, int nbuckets,
                                                        int* __restrict__ partial) {
    if (blockIdx.x < 80) {
        int id = blockIdx.x * 256 + threadIdx.x;
        if (id < 16384) {
            int n = id >> 7, k = id & 127;
            W1T[id] = bf16r(W1[k * 128 + n]);
        } else if (id < 20480) {
            int j = id - 16384;
            int n = j >> 7, k = j & 127;
            W2T[j] = bf16r(W2[k * 32 + n]);
        }
        return;
    }
    int blk = blockIdx.x - 80;
    __shared__ int hist[1024];
    int tid = threadIdx.x;
    for (int i = tid; i < nbuckets; i += 256) hist[i] = 0;
    __syncthreads();
    int base = blk * EPB;
    int tot = E + N;
    #pragma unroll
    for (int it = 0; it < EPB / 256; it++) {
        int i = base + it * 256 + tid;
        if (i < tot) {
            int d = (i < E) ? dst[i] : (i - E);   // self-loops appended
            atomicAdd(&hist[d >> 8], 1);          // LDS atomic
        }
    }
    __syncthreads();
    for (int b = tid; b < nbuckets; b += 256)
        partial[b * nblk1 + blk] = hist[b];       // bucket-major
}

// ================= generic in-place exclusive scan (3 kernels) =================

__global__ __launch_bounds__(256) void gscan_bsum(const int* __restrict__ arr,
                                                  int* __restrict__ psum, int M) {
    __shared__ int red[4];
    int tid = threadIdx.x;
    int idx = blockIdx.x * 256 + tid;
    int v = (idx < M) ? arr[idx] : 0;
    #pragma unroll
    for (int off = 1; off < 64; off <<= 1) v += __shfl_xor(v, off, 64);
    if ((tid & 63) == 0) red[tid >> 6] = v;
    __syncthreads();
    if (tid == 0) psum[blockIdx.x] = red[0] + red[1] + red[2] + red[3];
}

__global__ __launch_bounds__(1024) void gscan_psum(int* __restrict__ psum, int nb) {
    __shared__ int ws[16];
    int tid = threadIdx.x, lane = tid & 63, w = tid >> 6;
    int v = (tid < nb) ? psum[tid] : 0;
    int incl = v;
    #pragma unroll
    for (int off = 1; off < 64; off <<= 1) {
        int t = __shfl_up(incl, off, 64);
        if (lane >= off) incl += t;
    }
    if (lane == 63) ws[w] = incl;
    __syncthreads();
    int wbase = 0;
    #pragma unroll
    for (int j = 0; j < 16; j++) { if (j < w) wbase += ws[j]; }
    if (tid < nb) psum[tid] = wbase + incl - v;   // exclusive
}

__global__ __launch_bounds__(256) void gscan_final(int* __restrict__ arr,
                                                   const int* __restrict__ psum, int M) {
    __shared__ int ws[4];
    int tid = threadIdx.x, lane = tid & 63, w = tid >> 6;
    int idx = blockIdx.x * 256 + tid;
    int v = (idx < M) ? arr[idx] : 0;
    int incl = v;
    #pragma unroll
    for (int off = 1; off < 64; off <<= 1) {
        int t = __shfl_up(incl, off, 64);
        if (lane >= off) incl += t;
    }
    if (lane == 63) ws[w] = incl;
    __syncthreads();
    int wbase = 0;
    #pragma unroll
    for (int j = 0; j < 4; j++) { if (j < w) wbase += ws[j]; }
    if (idx < M) arr[idx] = psum[blockIdx.x] + wbase + incl - v;
}

// ================= p1_scatter =================

__global__ __launch_bounds__(256) void p1_scatter(const int* __restrict__ src,
                                                  const int* __restrict__ dst, int E, int N,
                                                  int nblk1, int nbuckets,
                                                  const int* __restrict__ scanned,
                                                  unsigned* __restrict__ pairs) {
    __shared__ int cursor[1024];
    int tid = threadIdx.x;
    for (int b = tid; b < nbuckets; b += 256)
        cursor[b] = scanned[b * nblk1 + blockIdx.x];
    __syncthreads();
    int base = blockIdx.x * EPB;
    int tot = E + N;
    #pragma unroll
    for (int it = 0; it < EPB / 256; it++) {
        int i = base + it * 256 + tid;
        if (i < tot) {
            int s = (i < E) ? src[i] : (i - E);
            int d = (i < E) ? dst[i] : (i - E);
            int pos = atomicAdd(&cursor[d >> 8], 1);  // LDS atomic w/ return
            pairs[pos] = ((unsigned)(d & 255) << 24) | (unsigned)s;
        }
    }
}

#define P2CAP 8192

// ======== fused kernel B: p2 (blocks 0..nbuckets-1) || gemm1 (rest) ========

__global__ __launch_bounds__(256) void p2_gemm1_kernel(
        const unsigned* __restrict__ pairs, const int* __restrict__ scanned,
        int nblk1, int nbuckets, int Etot, int N,
        int* __restrict__ rowptr, int* __restrict__ col,
        const float* __restrict__ x, const unsigned short* __restrict__ W1T,
        const float* __restrict__ a_s, const float* __restrict__ a_d,
        uint4* __restrict__ h1b, float* __restrict__ as1, float* __restrict__ ad1) {
    __shared__ char pool[49152];
    int tid = threadIdx.x;

    if ((int)blockIdx.x < nbuckets) {
        // ---------------- p2 branch ----------------
        unsigned* buf = (unsigned*)pool;                 // 32 KB
        int* cnt = (int*)(pool + 32768);
        int* cur = (int*)(pool + 33792);
        int* wsum = (int*)(pool + 34816);
        int b = blockIdx.x;
        int lane = tid & 63, w = tid >> 6;
        int bucketStart = scanned[b * nblk1];
        int bucketEnd = (b + 1 < nbuckets) ? scanned[(b + 1) * nblk1] : Etot;
        int sz = bucketEnd - bucketStart;
        bool inLds = (sz <= P2CAP);
        cnt[tid] = 0;
        if (inLds) {
            for (int i = tid; i < sz; i += 256) buf[i] = pairs[bucketStart + i];
        }
        __syncthreads();
        if (inLds) {
            for (int i = tid; i < sz; i += 256) atomicAdd(&cnt[buf[i] >> 24], 1);
        } else {
            for (int i = bucketStart + tid; i < bucketEnd; i += 256)
                atomicAdd(&cnt[pairs[i] >> 24], 1);
        }
        __syncthreads();
        int v = cnt[tid];
        int incl = v;
        #pragma unroll
        for (int off = 1; off < 64; off <<= 1) {
            int t = __shfl_up(incl, off, 64);
            if (lane >= off) incl += t;
        }
        if (lane == 63) wsum[w] = incl;
        __syncthreads();
        int wbase = 0;
        #pragma unroll
        for (int j = 0; j < 4; j++) { if (j < w) wbase += wsum[j]; }
        int base = bucketStart + wbase + incl - v;
        cur[tid] = base;
        int d = b * 256 + tid;
        if (d < N) rowptr[d] = base;
        if (b == nbuckets - 1 && tid == 0) rowptr[N] = Etot;
        __syncthreads();
        if (inLds) {
            for (int i = tid; i < sz; i += 256) {
                unsigned p = buf[i];
                int pos = atomicAdd(&cur[p >> 24], 1);
                col[pos] = (int)(p & 0xFFFFFFu);
            }
        } else {
            for (int i = bucketStart + tid; i < bucketEnd; i += 256) {
                unsigned p = pairs[i];
                int pos = atomicAdd(&cur[p >> 24], 1);
                col[pos] = (int)(p & 0xFFFFFFu);
            }
        }
        return;
    }

    // ---------------- gemm1 branch ----------------
    char* xs = pool;                    // 16 KB A tile / output tile
    char* wsm = pool + 16384;           // 32 KB W1T tile
    int row0 = ((int)blockIdx.x - nbuckets) * 64;

    #pragma unroll
    for (int it = 0; it < 8; it++) {
        int idx = it * 256 + tid;
        int n = idx >> 4, kq = idx & 15;
        uint4 v = ((const uint4*)W1T)[idx];
        *(uint4*)(wsm + SWZ(n, kq * 16)) = v;
    }
    #pragma unroll
    for (int it = 0; it < 8; it++) {
        int idx = it * 256 + tid;
        int r = idx >> 5, k4 = idx & 31;
        int row = row0 + r;
        float4 v = (row < N) ? ((const float4*)x)[(size_t)row * 32 + k4]
                             : make_float4(0.f, 0.f, 0.f, 0.f);
        uint2 p;
        p.x = pack_bf16x2(v.x, v.y);
        p.y = pack_bf16x2(v.z, v.w);
        *(uint2*)(xs + SWZ(r, k4 * 8)) = p;
    }
    __syncthreads();

    int wv = tid >> 6, lane = tid & 63;
    int r0 = wv * 16;
    int lm = lane & 15, lk = lane >> 4;

    bf16x8 afr[4];
    #pragma unroll
    for (int ks = 0; ks < 4; ks++) {
        int row = r0 + lm;
        afr[ks] = *(const bf16x8*)(xs + SWZ(row, ks * 64 + lk * 16));
    }
    f32x4 acc[8];
    #pragma unroll
    for (int nt = 0; nt < 8; nt++) acc[nt] = (f32x4){0.f, 0.f, 0.f, 0.f};

    #pragma unroll
    for (int nt = 0; nt < 8; nt++) {
        int c = nt * 16 + lm;
        #pragma unroll
        for (int ks = 0; ks < 4; ks++) {
            bf16x8 bfr = *(const bf16x8*)(wsm + SWZ(c, ks * 64 + lk * 16));
            acc[nt] = __builtin_amdgcn_mfma_f32_16x16x32_bf16(afr[ks], bfr, acc[nt], 0, 0, 0);
        }
    }
    __syncthreads();

    #pragma unroll
    for (int nt = 0; nt < 8; nt++) {
        int c = nt * 16 + lm;
        #pragma unroll
        for (int e = 0; e < 4; e++) {
            int row = r0 + lk * 4 + e;
            *(unsigned short*)(xs + SWZ(row, c * 2)) = bf16r(acc[nt][e]);
        }
    }
    __syncthreads();

    #pragma unroll
    for (int it = 0; it < 4; it++) {
        int idx = it * 256 + tid;
        int row = idx >> 4, q = idx & 15;
        if (row0 + row < N) {
            uint4 v = *(const uint4*)(xs + SWZ(row, q * 16));
            h1b[(size_t)(row0 + row) * 16 + q] = v;
        }
    }
    {
        int row = tid >> 2, h = tid & 3;
        if (row0 + row < N) {
            float sd = 0.f, dd = 0.f;
            #pragma unroll
            for (int q = 0; q < 4; q++) {
                uint4 v = *(const uint4*)(xs + SWZ(row, h * 64 + q * 16));
                unsigned uu[4] = {v.x, v.y, v.z, v.w};
                #pragma unroll
                for (int j = 0; j < 4; j++) {
                    int k = h * 32 + q * 8 + 2 * j;
                    sd = fmaf(bf_lo(uu[j]), a_s[k], sd);
                    sd = fmaf(bf_hi(uu[j]), a_s[k + 1], sd);
                    dd = fmaf(bf_lo(uu[j]), a_d[k], dd);
                    dd = fmaf(bf_hi(uu[j]), a_d[k + 1], dd);
                }
            }
            as1[(row0 + row) * 4 + h] = sd;
            ad1[(row0 + row) * 4 + h] = dd;
        }
    }
}

// ------- Layer 1 aggregation: scalar-offset gathers, lane-specialized exp,
//         predicated 8-batch tail (>=8 loads in flight for ALL edges) -------

__global__ __launch_bounds__(256) void agg1_kernel(const int* __restrict__ rowptr,
                                                   const int* __restrict__ col,
                                                   const unsigned* __restrict__ h1b,
                                                   const float* __restrict__ as1,
                                                   const float* __restrict__ ad1,
                                                   const float* __restrict__ b1,
                                                   unsigned* __restrict__ out1b, int N) {
    int lane = threadIdx.x & 63;
    int wid = __builtin_amdgcn_readfirstlane(threadIdx.x >> 6);
    int n = blockIdx.x * 4 + wid;
    if (n >= N) return;
    int hh = lane >> 4;                  // consumer head of channels 2*lane, 2*lane+1
    float4 adv = ((const float4*)ad1)[n];
    float adn = sel4(adv, hh);
    int ph8 = (lane >> 3) & 3;           // producer head for predicated-8 batches
    float adp = sel4(adv, ph8);
    Rsrc h1r = mkrsrc(h1b);
    Rsrc asr = mkrsrc(as1);
    int laneByte = lane << 2;
    int hhByte = hh << 2;
    int exbase = lane & 48;              // first lane of my head group (16-batch)
    int beg = __builtin_amdgcn_readfirstlane(rowptr[n]);
    int end = __builtin_amdgcn_readfirstlane(rowptr[n + 1]);
    float ax0 = 0.f, ay0 = 0.f, d0 = 0.f;
    float ax1 = 0.f, ay1 = 0.f, d1 = 0.f;
    float ax2 = 0.f, ay2 = 0.f, d2 = 0.f;
    float ax3 = 0.f, ay3 = 0.f, d3 = 0.f;
    int i = beg;
    for (; i + 16 <= end; i += 16) {
        // lane l computes exp for (edge l&15, head l>>4): 64 distinct, zero redundancy
        int myss = col[i + (lane & 15)];
        float myl = bufld_f32(asr, (myss << 4) + hhByte);
        float e = myl + adn;
        e = fmaxf(e, e * NEG_SLOPE);
        float myex = __expf(e);
        unsigned uu[16];
        #pragma unroll
        for (int j = 0; j < 16; j++) {
            int sj = col[i + j];                      // uniform -> scalar load
            uu[j] = bufld_u32s(h1r, laneByte, sj << 8);
        }
        float exj[16];
        #pragma unroll
        for (int j = 0; j < 16; j++) exj[j] = __shfl(myex, exbase + j, 64);
        #pragma unroll
        for (int j = 0; j < 16; j++) {
            float ex = exj[j];
            if ((j & 3) == 0)      { d0 += ex; ax0 = fmaf(ex, bf_lo(uu[j]), ax0); ay0 = fmaf(ex, bf_hi(uu[j]), ay0); }
            else if ((j & 3) == 1) { d1 += ex; ax1 = fmaf(ex, bf_lo(uu[j]), ax1); ay1 = fmaf(ex, bf_hi(uu[j]), ay1); }
            else if ((j & 3) == 2) { d2 += ex; ax2 = fmaf(ex, bf_lo(uu[j]), ax2); ay2 = fmaf(ex, bf_hi(uu[j]), ay2); }
            else                   { d3 += ex; ax3 = fmaf(ex, bf_lo(uu[j]), ax3); ay3 = fmaf(ex, bf_hi(uu[j]), ay3); }
        }
    }
    // predicated 8-batch tail: clamp to end-1 (valid — self-loops), zero ex for OOB slots
    for (; i < end; i += 8) {
        int lim = end - 1;
        int pe = i + (lane & 7);
        pe = pe <= lim ? pe : lim;
        int myss = col[pe];                           // per-lane (L1-hot)
        float myl = bufld_f32(asr, (myss << 4) + (ph8 << 2));
        float e = myl + adp;
        e = fmaxf(e, e * NEG_SLOPE);
        float myex = __expf(e);                       // lanes 0..31 cover 8 edges x 4 heads
        unsigned uu[8];
        #pragma unroll
        for (int j = 0; j < 8; j++) {
            int ej = i + j;
            ej = ej <= lim ? ej : lim;                // uniform
            int sj = col[ej];                         // scalar load
            uu[j] = bufld_u32s(h1r, laneByte, sj << 8);
        }
        #pragma unroll
        for (int j = 0; j < 8; j++) {
            float ex = __shfl(myex, (hh << 3) + j, 64);
            ex = (i + j < end) ? ex : 0.f;
            if ((j & 3) == 0)      { d0 += ex; ax0 = fmaf(ex, bf_lo(uu[j]), ax0); ay0 = fmaf(ex, bf_hi(uu[j]), ay0); }
            else if ((j & 3) == 1) { d1 += ex; ax1 = fmaf(ex, bf_lo(uu[j]), ax1); ay1 = fmaf(ex, bf_hi(uu[j]), ay1); }
            else if ((j & 3) == 2) { d2 += ex; ax2 = fmaf(ex, bf_lo(uu[j]), ax2); ay2 = fmaf(ex, bf_hi(uu[j]), ay2); }
            else                   { d3 += ex; ax3 = fmaf(ex, bf_lo(uu[j]), ax3); ay3 = fmaf(ex, bf_hi(uu[j]), ay3); }
        }
    }
    float den = (d0 + d1) + (d2 + d3);
    float ax = (ax0 + ax1) + (ax2 + ax3);
    float ay = (ay0 + ay1) + (ay2 + ay3);
    float2 bb = ((const float2*)b1)[lane];
    float ox = fmaxf(ax / den + bb.x, 0.f);
    float oy = fmaxf(ay / den + bb.y, 0.f);
    out1b[n * 64 + lane] = pack_bf16x2(ox, oy);
}

// ================= Layer 2 GEMM (MFMA bf16): h2 = relu_h @ W2, plus as2/ad2 =============

__global__ __launch_bounds__(256) void gemm2_kernel(const uint4* __restrict__ out1b,
                                                    const unsigned short* __restrict__ W2T,
                                                    const float* __restrict__ a_s,
                                                    const float* __restrict__ a_d,
                                                    uint4* __restrict__ h2b,
                                                    float* __restrict__ as2,
                                                    float* __restrict__ ad2, int N) {
    __shared__ char xs[16384];          // A tile / later h2 tile
    __shared__ char wsm[8192];          // W2T 32x128 bf16
    int tid = threadIdx.x;
    int row0 = blockIdx.x * 64;

    #pragma unroll
    for (int it = 0; it < 2; it++) {
        int idx = it * 256 + tid;
        int n = idx >> 4, kq = idx & 15;
        uint4 v = ((const uint4*)W2T)[idx];
        *(uint4*)(wsm + SWZ(n, kq * 16)) = v;
    }
    #pragma unroll
    for (int it = 0; it < 4; it++) {
        int idx = it * 256 + tid;
        int r = idx >> 4, q = idx & 15;
        int row = row0 + r;
        uint4 v = (row < N) ? out1b[(size_t)row * 16 + q] : make_uint4(0, 0, 0, 0);
        *(uint4*)(xs + SWZ(r, q * 16)) = v;
    }
    __syncthreads();

    int wv = tid >> 6, lane = tid & 63;
    int r0 = wv * 16;
    int lm = lane & 15, lk = lane >> 4;

    bf16x8 afr[4];
    #pragma unroll
    for (int ks = 0; ks < 4; ks++) {
        int row = r0 + lm;
        afr[ks] = *(const bf16x8*)(xs + SWZ(row, ks * 64 + lk * 16));
    }
    f32x4 acc[2];
    acc[0] = (f32x4){0.f, 0.f, 0.f, 0.f};
    acc[1] = (f32x4){0.f, 0.f, 0.f, 0.f};
    #pragma unroll
    for (int nt = 0; nt < 2; nt++) {
        int c = nt * 16 + lm;
        #pragma unroll
        for (int ks = 0; ks < 4; ks++) {
            bf16x8 bfr = *(const bf16x8*)(wsm + SWZ(c, ks * 64 + lk * 16));
            acc[nt] = __builtin_amdgcn_mfma_f32_16x16x32_bf16(afr[ks], bfr, acc[nt], 0, 0, 0);
        }
    }
    __syncthreads();

    #pragma unroll
    for (int nt = 0; nt < 2; nt++) {
        int c = nt * 16 + lm;
        #pragma unroll
        for (int e = 0; e < 4; e++) {
            int row = r0 + lk * 4 + e;
            *(unsigned short*)(xs + SWZ(row, c * 2)) = bf16r(acc[nt][e]);
        }
    }
    __syncthreads();

    {
        int row = tid >> 2, q = tid & 3;
        if (row0 + row < N) {
            uint4 v = *(const uint4*)(xs + SWZ(row, q * 16));
            h2b[(size_t)(row0 + row) * 4 + q] = v;
        }
    }
    if (tid < 64 && row0 + tid < N) {
        float sd = 0.f, dd = 0.f;
        #pragma unroll
        for (int q = 0; q < 4; q++) {
            uint4 v = *(const uint4*)(xs + SWZ(tid, q * 16));
            unsigned uu[4] = {v.x, v.y, v.z, v.w};
            #pragma unroll
            for (int j = 0; j < 4; j++) {
                int k = q * 8 + 2 * j;
                sd = fmaf(bf_lo(uu[j]), a_s[k], sd);
                sd = fmaf(bf_hi(uu[j]), a_s[k + 1], sd);
                dd = fmaf(bf_lo(uu[j]), a_d[k], dd);
                dd = fmaf(bf_hi(uu[j]), a_d[k + 1], dd);
            }
        }
        as2[row0 + tid] = sd;
        ad2[row0 + tid] = dd;
    }
}

// ---------------- Layer 2 aggregation: 8 edges/wave, 8 lanes x 4ch, buffer loads --------

#define A2SLOT(u, l)                                               \
    {                                                              \
        float e = l + adn;                                         \
        e = fmaxf(e, e * NEG_SLOPE);                               \
        float ex = __expf(e);                                      \
        den += ex;                                                 \
        a0 = fmaf(ex, bf_lo(u.x), a0);                             \
        a1 = fmaf(ex, bf_hi(u.x), a1);                             \
        a2 = fmaf(ex, bf_lo(u.y), a2);                             \
        a3 = fmaf(ex, bf_hi(u.y), a3);                             \
    }

__global__ __launch_bounds__(256) void agg2_kernel(const int* __restrict__ rowptr,
                                                   const int* __restrict__ col,
                                                   const unsigned* __restrict__ h2b,
                                                   const float* __restrict__ as2,
                                                   const float* __restrict__ ad2,
                                                   const float* __restrict__ b2,
                                                   float* __restrict__ out, int N) {
    int lane = threadIdx.x & 63;
    int wid = __builtin_amdgcn_readfirstlane(threadIdx.x >> 6);
    int n = blockIdx.x * 4 + wid;
    if (n >= N) return;
    int q8 = lane >> 3;                  // edge slot 0..7
    int cl = lane & 7;                   // channel quad: channels 4*cl .. 4*cl+3
    Rsrc h2r = mkrsrc(h2b);
    Rsrc asr = mkrsrc(as2);
    int clByte = cl << 3;
    float adn = ad2[n];
    int beg = __builtin_amdgcn_readfirstlane(rowptr[n]);
    int end = __builtin_amdgcn_readfirstlane(rowptr[n + 1]);
    float a0 = 0.f, a1 = 0.f, a2 = 0.f, a3 = 0.f, den = 0.f;
    int i = beg;
    for (; i + 16 <= end; i += 16) {
        int e0 = i + q8, e1 = i + 8 + q8;
        int s0 = col[e0], s1 = col[e1];
        uint2 u0 = bufld_u64(h2r, (s0 << 6) + clByte);
        uint2 u1 = bufld_u64(h2r, (s1 << 6) + clByte);
        float l0 = bufld_f32(asr, s0 << 2);
        float l1 = bufld_f32(asr, s1 << 2);
        A2SLOT(u0, l0) A2SLOT(u1, l1)
    }
    for (; i < end; i += 8) {
        int e = i + q8;
        if (e < end) {
            int s = col[e];
            uint2 u = bufld_u64(h2r, (s << 6) + clByte);
            float l = bufld_f32(asr, s << 2);
            A2SLOT(u, l)
        }
    }
    den += __shfl_xor(den, 8, 64);
    den += __shfl_xor(den, 16, 64);
    den += __shfl_xor(den, 32, 64);
    a0 += __shfl_xor(a0, 8, 64);  a0 += __shfl_xor(a0, 16, 64);  a0 += __shfl_xor(a0, 32, 64);
    a1 += __shfl_xor(a1, 8, 64);  a1 += __shfl_xor(a1, 16, 64);  a1 += __shfl_xor(a1, 32, 64);
    a2 += __shfl_xor(a2, 8, 64);  a2 += __shfl_xor(a2, 16, 64);  a2 += __shfl_xor(a2, 32, 64);
    a3 += __shfl_xor(a3, 8, 64);  a3 += __shfl_xor(a3, 16, 64);  a3 += __shfl_xor(a3, 32, 64);
    if (q8 == 0) {
        float4 bb = ((const float4*)b2)[cl];
        float4 o;
        o.x = a0 / den + bb.x;
        o.y = a1 / den + bb.y;
        o.z = a2 / den + bb.z;
        o.w = a3 / den + bb.w;
        ((float4*)out)[n * 8 + cl] = o;
    }
}

// ---------------- launch ----------------

extern "C" void kernel_launch(void* const* d_in, const int* in_sizes, int n_in,
                              void* d_out, int out_size, void* d_ws, size_t ws_size,
                              hipStream_t stream) {
    const float* x    = (const float*)d_in[0];
    const int*   ei   = (const int*)d_in[1];
    const float* W1   = (const float*)d_in[2];
    const float* a_s1 = (const float*)d_in[3];
    const float* a_d1 = (const float*)d_in[4];
    const float* b1   = (const float*)d_in[5];
    const float* W2   = (const float*)d_in[6];
    const float* a_s2 = (const float*)d_in[7];
    const float* a_d2 = (const float*)d_in[8];
    const float* b2   = (const float*)d_in[9];

    int N = in_sizes[0] / 128;
    int E = in_sizes[1] / 2;
    const int* srcA = ei;
    const int* dstA = ei + E;
    int Etot = E + N;

    char* ws = (char*)d_ws;
    size_t off = 0;
    auto alloc = [&](size_t bytes) {
        void* p = ws + off;
        off += (bytes + 255) & ~(size_t)255;
        return p;
    };
    unsigned* h1b   = (unsigned*)alloc((size_t)N * 128 * 2);
    unsigned* out1b = (unsigned*)alloc((size_t)N * 128 * 2);
    unsigned* h2b   = (unsigned*)alloc((size_t)N * 32 * 2);
    float* as1      = (float*)alloc((size_t)N * 4 * 4);
    float* ad1      = (float*)alloc((size_t)N * 4 * 4);
    float* as2      = (float*)alloc((size_t)N * 4);
    float* ad2      = (float*)alloc((size_t)N * 4);
    int*   rowptr   = (int*)alloc((size_t)(N + 1) * 4);
    int*   col      = (int*)alloc((size_t)Etot * 4);
    unsigned* pairs = (unsigned*)alloc((size_t)Etot * 4);
    unsigned short* W1T = (unsigned short*)alloc(128 * 128 * 2);
    unsigned short* W2T = (unsigned short*)alloc(32 * 128 * 2);

    int nbuckets = (N + 255) >> 8;                 // 391
    int nblk1 = (Etot + EPB - 1) / EPB;            // 104
    int M = nbuckets * nblk1;                      // ~41K
    int*   partial = (int*)alloc((size_t)M * 4);
    int nbs = (M + 255) / 256;                     // 159
    int*   psum    = (int*)alloc((size_t)1024 * 4);

    int gblocks = (N + 63) / 64;

    // wcvt || p1_hist
    hipLaunchKernelGGL(wcvt_hist_kernel, dim3(80 + nblk1), dim3(256), 0, stream,
                       W1, W2, W1T, W2T, dstA, E, N, nblk1, nbuckets, partial);
    // scan
    hipLaunchKernelGGL(gscan_bsum, dim3(nbs), dim3(256), 0, stream, partial, psum, M);
    hipLaunchKernelGGL(gscan_psum, dim3(1), dim3(1024), 0, stream, psum, nbs);
    hipLaunchKernelGGL(gscan_final, dim3(nbs), dim3(256), 0, stream, partial, psum, M);
    // scatter
    hipLaunchKernelGGL(p1_scatter, dim3(nblk1), dim3(256), 0, stream,
                       srcA, dstA, E, N, nblk1, nbuckets, partial, pairs);
    // p2 || gemm1
    hipLaunchKernelGGL(p2_gemm1_kernel, dim3(nbuckets + gblocks), dim3(256), 0, stream,
                       pairs, partial, nblk1, nbuckets, Etot, N, rowptr, col,
                       x, W1T, a_s1, a_d1, (uint4*)h1b, as1, ad1);

    // GAT layers
    hipLaunchKernelGGL(agg1_kernel, dim3((N + 3) / 4), dim3(256), 0, stream,
                       rowptr, col, h1b, as1, ad1, b1, out1b, N);
    hipLaunchKernelGGL(gemm2_kernel, dim3(gblocks), dim3(256), 0, stream,
                       (const uint4*)out1b, W2T, a_s2, a_d2, (uint4*)h2b, as2, ad2, N);
    hipLaunchKernelGGL(agg2_kernel, dim3((N + 3) / 4), dim3(256), 0, stream,
                       rowptr, col, h2b, as2, ad2, b2, (float*)d_out, N);
}

// Round 14
// 194.614 us; speedup vs baseline: 1.1271x; 1.1271x over previous
//
#include <hip/hip_runtime.h>
#include <math.h>

#define NEG_SLOPE 0.2f
#define EPB 8192            // edges per P1 block

typedef __attribute__((ext_vector_type(8))) short bf16x8;
typedef __attribute__((ext_vector_type(4))) float f32x4;

__device__ __forceinline__ unsigned pack_bf16x2(float a, float b) {
    unsigned ua = __float_as_uint(a);
    unsigned ub = __float_as_uint(b);
    ua += 0x7FFFu + ((ua >> 16) & 1u);     // RNE
    ub += 0x7FFFu + ((ub >> 16) & 1u);
    return (ua >> 16) | (ub & 0xFFFF0000u);
}
__device__ __forceinline__ unsigned short bf16r(float f) {
    unsigned u = __float_as_uint(f);
    u += 0x7FFFu + ((u >> 16) & 1u);
    return (unsigned short)(u >> 16);
}
__device__ __forceinline__ float bf_lo(unsigned u) { return __uint_as_float(u << 16); }
__device__ __forceinline__ float bf_hi(unsigned u) { return __uint_as_float(u & 0xFFFF0000u); }

// ---- SRSRC buffer loads (32-bit voffset + SGPR soffset: near-zero VALU gathers) ----
#if defined(__has_builtin)
#if __has_builtin(__builtin_amdgcn_make_buffer_rsrc) && \
    __has_builtin(__builtin_amdgcn_raw_ptr_buffer_load_b32) && \
    __has_builtin(__builtin_amdgcn_raw_ptr_buffer_load_b64)
#define USE_BUFLD 1
#endif
#endif

#ifdef USE_BUFLD
typedef __amdgpu_buffer_rsrc_t Rsrc;
typedef __attribute__((ext_vector_type(2))) unsigned uint2v;
__device__ __forceinline__ Rsrc mkrsrc(const void* p) {
    return __builtin_amdgcn_make_buffer_rsrc((void*)p, (short)0, -1, 0x00020000);
}
__device__ __forceinline__ unsigned bufld_u32(Rsrc r, int voff) {
    return __builtin_amdgcn_raw_ptr_buffer_load_b32(r, voff, 0, 0);
}
__device__ __forceinline__ unsigned bufld_u32s(Rsrc r, int voff, int soff) {
    return __builtin_amdgcn_raw_ptr_buffer_load_b32(r, voff, soff, 0);
}
__device__ __forceinline__ float bufld_f32(Rsrc r, int voff) {
    return __uint_as_float(__builtin_amdgcn_raw_ptr_buffer_load_b32(r, voff, 0, 0));
}
__device__ __forceinline__ uint2 bufld_u64(Rsrc r, int voff) {
    uint2v v = __builtin_amdgcn_raw_ptr_buffer_load_b64(r, voff, 0, 0);
    return make_uint2(v.x, v.y);
}
#else
struct Rsrc { const char* p; };
__device__ __forceinline__ Rsrc mkrsrc(const void* p) { Rsrc r; r.p = (const char*)p; return r; }
__device__ __forceinline__ unsigned bufld_u32(Rsrc r, int voff) { return *(const unsigned*)(r.p + voff); }
__device__ __forceinline__ unsigned bufld_u32s(Rsrc r, int voff, int soff) { return *(const unsigned*)(r.p + voff + soff); }
__device__ __forceinline__ float bufld_f32(Rsrc r, int voff) { return *(const float*)(r.p + voff); }
__device__ __forceinline__ uint2 bufld_u64(Rsrc r, int voff) { return *(const uint2*)(r.p + voff); }
#endif

// LDS tile addressing: row stride 256B, XOR swizzle spreads 16 rows over 16B slots
#define SWZ(row, byteoff) ((((row) * 256) + (byteoff)) ^ (((row) & 15) << 4))

// ======== fused kernel A: wcvt (blocks 0..79) || p1_hist (blocks 80..) ========

__global__ __launch_bounds__(256) void wcvt_hist_kernel(const float* __restrict__ W1,
                                                        const float* __restrict__ W2,
                                                        unsigned short* __restrict__ W1T,
                                                        unsigned short* __restrict__ W2T,
                                                        const int* __restrict__ dst,
                                                        int E, int N, int nblk1, int nbuckets,
                                                        int* __restrict__ partial) {
    if (blockIdx.x < 80) {
        int id = blockIdx.x * 256 + threadIdx.x;
        if (id < 16384) {
            int n = id >> 7, k = id & 127;
            W1T[id] = bf16r(W1[k * 128 + n]);
        } else if (id < 20480) {
            int j = id - 16384;
            int n = j >> 7, k = j & 127;
            W2T[j] = bf16r(W2[k * 32 + n]);
        }
        return;
    }
    int blk = blockIdx.x - 80;
    __shared__ int hist[1024];
    int tid = threadIdx.x;
    for (int i = tid; i < nbuckets; i += 256) hist[i] = 0;
    __syncthreads();
    int base = blk * EPB;
    int tot = E + N;
    #pragma unroll
    for (int it = 0; it < EPB / 256; it++) {
        int i = base + it * 256 + tid;
        if (i < tot) {
            int d = (i < E) ? dst[i] : (i - E);   // self-loops appended
            atomicAdd(&hist[d >> 8], 1);          // LDS atomic
        }
    }
    __syncthreads();
    for (int b = tid; b < nbuckets; b += 256)
        partial[b * nblk1 + blk] = hist[b];       // bucket-major
}

// ================= generic in-place exclusive scan (3 kernels) =================

__global__ __launch_bounds__(256) void gscan_bsum(const int* __restrict__ arr,
                                                  int* __restrict__ psum, int M) {
    __shared__ int red[4];
    int tid = threadIdx.x;
    int idx = blockIdx.x * 256 + tid;
    int v = (idx < M) ? arr[idx] : 0;
    #pragma unroll
    for (int off = 1; off < 64; off <<= 1) v += __shfl_xor(v, off, 64);
    if ((tid & 63) == 0) red[tid >> 6] = v;
    __syncthreads();
    if (tid == 0) psum[blockIdx.x] = red[0] + red[1] + red[2] + red[3];
}

__global__ __launch_bounds__(1024) void gscan_psum(int* __restrict__ psum, int nb) {
    __shared__ int ws[16];
    int tid = threadIdx.x, lane = tid & 63, w = tid >> 6;
    int v = (tid < nb) ? psum[tid] : 0;
    int incl = v;
    #pragma unroll
    for (int off = 1; off < 64; off <<= 1) {
        int t = __shfl_up(incl, off, 64);
        if (lane >= off) incl += t;
    }
    if (lane == 63) ws[w] = incl;
    __syncthreads();
    int wbase = 0;
    #pragma unroll
    for (int j = 0; j < 16; j++) { if (j < w) wbase += ws[j]; }
    if (tid < nb) psum[tid] = wbase + incl - v;   // exclusive
}

__global__ __launch_bounds__(256) void gscan_final(int* __restrict__ arr,
                                                   const int* __restrict__ psum, int M) {
    __shared__ int ws[4];
    int tid = threadIdx.x, lane = tid & 63, w = tid >> 6;
    int idx = blockIdx.x * 256 + tid;
    int v = (idx < M) ? arr[idx] : 0;
    int incl = v;
    #pragma unroll
    for (int off = 1; off < 64; off <<= 1) {
        int t = __shfl_up(incl, off, 64);
        if (lane >= off) incl += t;
    }
    if (lane == 63) ws[w] = incl;
    __syncthreads();
    int wbase = 0;
    #pragma unroll
    for (int j = 0; j < 4; j++) { if (j < w) wbase += ws[j]; }
    if (idx < M) arr[idx] = psum[blockIdx.x] + wbase + incl - v;
}

// ================= p1_scatter =================

__global__ __launch_bounds__(256) void p1_scatter(const int* __restrict__ src,
                                                  const int* __restrict__ dst, int E, int N,
                                                  int nblk1, int nbuckets,
                                                  const int* __restrict__ scanned,
                                                  unsigned* __restrict__ pairs) {
    __shared__ int cursor[1024];
    int tid = threadIdx.x;
    for (int b = tid; b < nbuckets; b += 256)
        cursor[b] = scanned[b * nblk1 + blockIdx.x];
    __syncthreads();
    int base = blockIdx.x * EPB;
    int tot = E + N;
    #pragma unroll
    for (int it = 0; it < EPB / 256; it++) {
        int i = base + it * 256 + tid;
        if (i < tot) {
            int s = (i < E) ? src[i] : (i - E);
            int d = (i < E) ? dst[i] : (i - E);
            int pos = atomicAdd(&cursor[d >> 8], 1);  // LDS atomic w/ return
            pairs[pos] = ((unsigned)(d & 255) << 24) | (unsigned)s;
        }
    }
}

#define P2CAP 8192

// ======== fused kernel B: p2 (blocks 0..nbuckets-1) || gemm1 (rest) ========

__global__ __launch_bounds__(256) void p2_gemm1_kernel(
        const unsigned* __restrict__ pairs, const int* __restrict__ scanned,
        int nblk1, int nbuckets, int Etot, int N,
        int* __restrict__ rowptr, int* __restrict__ col,
        const float* __restrict__ x, const unsigned short* __restrict__ W1T,
        const float* __restrict__ a_s, const float* __restrict__ a_d,
        uint4* __restrict__ h1b, float* __restrict__ as1, float* __restrict__ ad1) {
    __shared__ char pool[49152];
    int tid = threadIdx.x;

    if ((int)blockIdx.x < nbuckets) {
        // ---------------- p2 branch ----------------
        unsigned* buf = (unsigned*)pool;                 // 32 KB
        int* cnt = (int*)(pool + 32768);
        int* cur = (int*)(pool + 33792);
        int* wsum = (int*)(pool + 34816);
        int b = blockIdx.x;
        int lane = tid & 63, w = tid >> 6;
        int bucketStart = scanned[b * nblk1];
        int bucketEnd = (b + 1 < nbuckets) ? scanned[(b + 1) * nblk1] : Etot;
        int sz = bucketEnd - bucketStart;
        bool inLds = (sz <= P2CAP);
        cnt[tid] = 0;
        if (inLds) {
            for (int i = tid; i < sz; i += 256) buf[i] = pairs[bucketStart + i];
        }
        __syncthreads();
        if (inLds) {
            for (int i = tid; i < sz; i += 256) atomicAdd(&cnt[buf[i] >> 24], 1);
        } else {
            for (int i = bucketStart + tid; i < bucketEnd; i += 256)
                atomicAdd(&cnt[pairs[i] >> 24], 1);
        }
        __syncthreads();
        int v = cnt[tid];
        int incl = v;
        #pragma unroll
        for (int off = 1; off < 64; off <<= 1) {
            int t = __shfl_up(incl, off, 64);
            if (lane >= off) incl += t;
        }
        if (lane == 63) wsum[w] = incl;
        __syncthreads();
        int wbase = 0;
        #pragma unroll
        for (int j = 0; j < 4; j++) { if (j < w) wbase += wsum[j]; }
        int base = bucketStart + wbase + incl - v;
        cur[tid] = base;
        int d = b * 256 + tid;
        if (d < N) rowptr[d] = base;
        if (b == nbuckets - 1 && tid == 0) rowptr[N] = Etot;
        __syncthreads();
        if (inLds) {
            for (int i = tid; i < sz; i += 256) {
                unsigned p = buf[i];
                int pos = atomicAdd(&cur[p >> 24], 1);
                col[pos] = (int)(p & 0xFFFFFFu);
            }
        } else {
            for (int i = bucketStart + tid; i < bucketEnd; i += 256) {
                unsigned p = pairs[i];
                int pos = atomicAdd(&cur[p >> 24], 1);
                col[pos] = (int)(p & 0xFFFFFFu);
            }
        }
        return;
    }

    // ---------------- gemm1 branch ----------------
    char* xs = pool;                    // 16 KB A tile / output tile
    char* wsm = pool + 16384;           // 32 KB W1T tile
    int row0 = ((int)blockIdx.x - nbuckets) * 64;

    #pragma unroll
    for (int it = 0; it < 8; it++) {
        int idx = it * 256 + tid;
        int n = idx >> 4, kq = idx & 15;
        uint4 v = ((const uint4*)W1T)[idx];
        *(uint4*)(wsm + SWZ(n, kq * 16)) = v;
    }
    #pragma unroll
    for (int it = 0; it < 8; it++) {
        int idx = it * 256 + tid;
        int r = idx >> 5, k4 = idx & 31;
        int row = row0 + r;
        float4 v = (row < N) ? ((const float4*)x)[(size_t)row * 32 + k4]
                             : make_float4(0.f, 0.f, 0.f, 0.f);
        uint2 p;
        p.x = pack_bf16x2(v.x, v.y);
        p.y = pack_bf16x2(v.z, v.w);
        *(uint2*)(xs + SWZ(r, k4 * 8)) = p;
    }
    __syncthreads();

    int wv = tid >> 6, lane = tid & 63;
    int r0 = wv * 16;
    int lm = lane & 15, lk = lane >> 4;

    bf16x8 afr[4];
    #pragma unroll
    for (int ks = 0; ks < 4; ks++) {
        int row = r0 + lm;
        afr[ks] = *(const bf16x8*)(xs + SWZ(row, ks * 64 + lk * 16));
    }
    f32x4 acc[8];
    #pragma unroll
    for (int nt = 0; nt < 8; nt++) acc[nt] = (f32x4){0.f, 0.f, 0.f, 0.f};

    #pragma unroll
    for (int nt = 0; nt < 8; nt++) {
        int c = nt * 16 + lm;
        #pragma unroll
        for (int ks = 0; ks < 4; ks++) {
            bf16x8 bfr = *(const bf16x8*)(wsm + SWZ(c, ks * 64 + lk * 16));
            acc[nt] = __builtin_amdgcn_mfma_f32_16x16x32_bf16(afr[ks], bfr, acc[nt], 0, 0, 0);
        }
    }
    __syncthreads();

    #pragma unroll
    for (int nt = 0; nt < 8; nt++) {
        int c = nt * 16 + lm;
        #pragma unroll
        for (int e = 0; e < 4; e++) {
            int row = r0 + lk * 4 + e;
            *(unsigned short*)(xs + SWZ(row, c * 2)) = bf16r(acc[nt][e]);
        }
    }
    __syncthreads();

    #pragma unroll
    for (int it = 0; it < 4; it++) {
        int idx = it * 256 + tid;
        int row = idx >> 4, q = idx & 15;
        if (row0 + row < N) {
            uint4 v = *(const uint4*)(xs + SWZ(row, q * 16));
            h1b[(size_t)(row0 + row) * 16 + q] = v;
        }
    }
    {
        int row = tid >> 2, h = tid & 3;
        if (row0 + row < N) {
            float sd = 0.f, dd = 0.f;
            #pragma unroll
            for (int q = 0; q < 4; q++) {
                uint4 v = *(const uint4*)(xs + SWZ(row, h * 64 + q * 16));
                unsigned uu[4] = {v.x, v.y, v.z, v.w};
                #pragma unroll
                for (int j = 0; j < 4; j++) {
                    int k = h * 32 + q * 8 + 2 * j;
                    sd = fmaf(bf_lo(uu[j]), a_s[k], sd);
                    sd = fmaf(bf_hi(uu[j]), a_s[k + 1], sd);
                    dd = fmaf(bf_lo(uu[j]), a_d[k], dd);
                    dd = fmaf(bf_hi(uu[j]), a_d[k + 1], dd);
                }
            }
            as1[(row0 + row) * 4 + h] = sd;
            ad1[(row0 + row) * 4 + h] = dd;
        }
    }
}

// ------- Layer 1 aggregation: scalar-offset gathers, lane-specialized exp -------
// col[i+j] is wave-uniform -> s_load; gather address = SGPR(sj<<8) + VGPR(laneByte).

__global__ __launch_bounds__(256) void agg1_kernel(const int* __restrict__ rowptr,
                                                   const int* __restrict__ col,
                                                   const unsigned* __restrict__ h1b,
                                                   const float* __restrict__ as1,
                                                   const float* __restrict__ ad1,
                                                   const float* __restrict__ b1,
                                                   unsigned* __restrict__ out1b, int N) {
    int lane = threadIdx.x & 63;
    int wid = __builtin_amdgcn_readfirstlane(threadIdx.x >> 6);
    int n = blockIdx.x * 4 + wid;
    if (n >= N) return;
    int hh = lane >> 4;                  // head of channels 2*lane, 2*lane+1
    float adn = ad1[n * 4 + hh];
    Rsrc h1r = mkrsrc(h1b);
    Rsrc asr = mkrsrc(as1);
    int laneByte = lane << 2;
    int hhByte = hh << 2;
    int exbase = lane & 48;              // first lane of my head group
    int beg = __builtin_amdgcn_readfirstlane(rowptr[n]);
    int end = __builtin_amdgcn_readfirstlane(rowptr[n + 1]);
    float ax0 = 0.f, ay0 = 0.f, d0 = 0.f;
    float ax1 = 0.f, ay1 = 0.f, d1 = 0.f;
    float ax2 = 0.f, ay2 = 0.f, d2 = 0.f;
    float ax3 = 0.f, ay3 = 0.f, d3 = 0.f;
    int i = beg;
    for (; i + 16 <= end; i += 16) {
        // lane l computes exp for (edge l&15, head l>>4): 64 distinct, zero redundancy
        int myss = col[i + (lane & 15)];
        float myl = bufld_f32(asr, (myss << 4) + hhByte);
        float e = myl + adn;
        e = fmaxf(e, e * NEG_SLOPE);
        float myex = __expf(e);
        unsigned uu[16];
        #pragma unroll
        for (int j = 0; j < 16; j++) {
            int sj = col[i + j];                      // uniform -> scalar load
            uu[j] = bufld_u32s(h1r, laneByte, sj << 8);
        }
        float exj[16];
        #pragma unroll
        for (int j = 0; j < 16; j++) exj[j] = __shfl(myex, exbase + j, 64);
        #pragma unroll
        for (int j = 0; j < 16; j++) {
            float ex = exj[j];
            if ((j & 3) == 0)      { d0 += ex; ax0 = fmaf(ex, bf_lo(uu[j]), ax0); ay0 = fmaf(ex, bf_hi(uu[j]), ay0); }
            else if ((j & 3) == 1) { d1 += ex; ax1 = fmaf(ex, bf_lo(uu[j]), ax1); ay1 = fmaf(ex, bf_hi(uu[j]), ay1); }
            else if ((j & 3) == 2) { d2 += ex; ax2 = fmaf(ex, bf_lo(uu[j]), ax2); ay2 = fmaf(ex, bf_hi(uu[j]), ay2); }
            else                   { d3 += ex; ax3 = fmaf(ex, bf_lo(uu[j]), ax3); ay3 = fmaf(ex, bf_hi(uu[j]), ay3); }
        }
    }
    for (; i + 4 <= end; i += 4) {
        unsigned uu[4];
        float ll[4];
        #pragma unroll
        for (int j = 0; j < 4; j++) {
            int sj = col[i + j];
            uu[j] = bufld_u32s(h1r, laneByte, sj << 8);
            ll[j] = bufld_f32(asr, (sj << 4) + hhByte);
        }
        #pragma unroll
        for (int j = 0; j < 4; j++) {
            float e = ll[j] + adn;
            e = fmaxf(e, e * NEG_SLOPE);
            float ex = __expf(e);
            if (j == 0)      { d0 += ex; ax0 = fmaf(ex, bf_lo(uu[j]), ax0); ay0 = fmaf(ex, bf_hi(uu[j]), ay0); }
            else if (j == 1) { d1 += ex; ax1 = fmaf(ex, bf_lo(uu[j]), ax1); ay1 = fmaf(ex, bf_hi(uu[j]), ay1); }
            else if (j == 2) { d2 += ex; ax2 = fmaf(ex, bf_lo(uu[j]), ax2); ay2 = fmaf(ex, bf_hi(uu[j]), ay2); }
            else             { d3 += ex; ax3 = fmaf(ex, bf_lo(uu[j]), ax3); ay3 = fmaf(ex, bf_hi(uu[j]), ay3); }
        }
    }
    for (; i < end; i++) {
        int s = col[i];
        unsigned u = bufld_u32s(h1r, laneByte, s << 8);
        float l = bufld_f32(asr, (s << 4) + hhByte);
        float e = l + adn;
        e = fmaxf(e, e * NEG_SLOPE);
        float ex = __expf(e);
        d0 += ex;
        ax0 = fmaf(ex, bf_lo(u), ax0);
        ay0 = fmaf(ex, bf_hi(u), ay0);
    }
    float den = (d0 + d1) + (d2 + d3);
    float ax = (ax0 + ax1) + (ax2 + ax3);
    float ay = (ay0 + ay1) + (ay2 + ay3);
    float2 bb = ((const float2*)b1)[lane];
    float ox = fmaxf(ax / den + bb.x, 0.f);
    float oy = fmaxf(ay / den + bb.y, 0.f);
    out1b[n * 64 + lane] = pack_bf16x2(ox, oy);
}

// ================= Layer 2 GEMM (MFMA bf16): h2 = relu_h @ W2, plus as2/ad2 =============

__global__ __launch_bounds__(256) void gemm2_kernel(const uint4* __restrict__ out1b,
                                                    const unsigned short* __restrict__ W2T,
                                                    const float* __restrict__ a_s,
                                                    const float* __restrict__ a_d,
                                                    uint4* __restrict__ h2b,
                                                    float* __restrict__ as2,
                                                    float* __restrict__ ad2, int N) {
    __shared__ char xs[16384];          // A tile / later h2 tile
    __shared__ char wsm[8192];          // W2T 32x128 bf16
    int tid = threadIdx.x;
    int row0 = blockIdx.x * 64;

    #pragma unroll
    for (int it = 0; it < 2; it++) {
        int idx = it * 256 + tid;
        int n = idx >> 4, kq = idx & 15;
        uint4 v = ((const uint4*)W2T)[idx];
        *(uint4*)(wsm + SWZ(n, kq * 16)) = v;
    }
    #pragma unroll
    for (int it = 0; it < 4; it++) {
        int idx = it * 256 + tid;
        int r = idx >> 4, q = idx & 15;
        int row = row0 + r;
        uint4 v = (row < N) ? out1b[(size_t)row * 16 + q] : make_uint4(0, 0, 0, 0);
        *(uint4*)(xs + SWZ(r, q * 16)) = v;
    }
    __syncthreads();

    int wv = tid >> 6, lane = tid & 63;
    int r0 = wv * 16;
    int lm = lane & 15, lk = lane >> 4;

    bf16x8 afr[4];
    #pragma unroll
    for (int ks = 0; ks < 4; ks++) {
        int row = r0 + lm;
        afr[ks] = *(const bf16x8*)(xs + SWZ(row, ks * 64 + lk * 16));
    }
    f32x4 acc[2];
    acc[0] = (f32x4){0.f, 0.f, 0.f, 0.f};
    acc[1] = (f32x4){0.f, 0.f, 0.f, 0.f};
    #pragma unroll
    for (int nt = 0; nt < 2; nt++) {
        int c = nt * 16 + lm;
        #pragma unroll
        for (int ks = 0; ks < 4; ks++) {
            bf16x8 bfr = *(const bf16x8*)(wsm + SWZ(c, ks * 64 + lk * 16));
            acc[nt] = __builtin_amdgcn_mfma_f32_16x16x32_bf16(afr[ks], bfr, acc[nt], 0, 0, 0);
        }
    }
    __syncthreads();

    #pragma unroll
    for (int nt = 0; nt < 2; nt++) {
        int c = nt * 16 + lm;
        #pragma unroll
        for (int e = 0; e < 4; e++) {
            int row = r0 + lk * 4 + e;
            *(unsigned short*)(xs + SWZ(row, c * 2)) = bf16r(acc[nt][e]);
        }
    }
    __syncthreads();

    {
        int row = tid >> 2, q = tid & 3;
        if (row0 + row < N) {
            uint4 v = *(const uint4*)(xs + SWZ(row, q * 16));
            h2b[(size_t)(row0 + row) * 4 + q] = v;
        }
    }
    if (tid < 64 && row0 + tid < N) {
        float sd = 0.f, dd = 0.f;
        #pragma unroll
        for (int q = 0; q < 4; q++) {
            uint4 v = *(const uint4*)(xs + SWZ(tid, q * 16));
            unsigned uu[4] = {v.x, v.y, v.z, v.w};
            #pragma unroll
            for (int j = 0; j < 4; j++) {
                int k = q * 8 + 2 * j;
                sd = fmaf(bf_lo(uu[j]), a_s[k], sd);
                sd = fmaf(bf_hi(uu[j]), a_s[k + 1], sd);
                dd = fmaf(bf_lo(uu[j]), a_d[k], dd);
                dd = fmaf(bf_hi(uu[j]), a_d[k + 1], dd);
            }
        }
        as2[row0 + tid] = sd;
        ad2[row0 + tid] = dd;
    }
}

// ---------------- Layer 2 aggregation: 8 edges/wave, 8 lanes x 4ch, buffer loads --------

#define A2SLOT(u, l)                                               \
    {                                                              \
        float e = l + adn;                                         \
        e = fmaxf(e, e * NEG_SLOPE);                               \
        float ex = __expf(e);                                      \
        den += ex;                                                 \
        a0 = fmaf(ex, bf_lo(u.x), a0);                             \
        a1 = fmaf(ex, bf_hi(u.x), a1);                             \
        a2 = fmaf(ex, bf_lo(u.y), a2);                             \
        a3 = fmaf(ex, bf_hi(u.y), a3);                             \
    }

__global__ __launch_bounds__(256) void agg2_kernel(const int* __restrict__ rowptr,
                                                   const int* __restrict__ col,
                                                   const unsigned* __restrict__ h2b,
                                                   const float* __restrict__ as2,
                                                   const float* __restrict__ ad2,
                                                   const float* __restrict__ b2,
                                                   float* __restrict__ out, int N) {
    int lane = threadIdx.x & 63;
    int wid = __builtin_amdgcn_readfirstlane(threadIdx.x >> 6);
    int n = blockIdx.x * 4 + wid;
    if (n >= N) return;
    int q8 = lane >> 3;                  // edge slot 0..7
    int cl = lane & 7;                   // channel quad: channels 4*cl .. 4*cl+3
    Rsrc h2r = mkrsrc(h2b);
    Rsrc asr = mkrsrc(as2);
    int clByte = cl << 3;
    float adn = ad2[n];
    int beg = __builtin_amdgcn_readfirstlane(rowptr[n]);
    int end = __builtin_amdgcn_readfirstlane(rowptr[n + 1]);
    float a0 = 0.f, a1 = 0.f, a2 = 0.f, a3 = 0.f, den = 0.f;
    int i = beg;
    for (; i + 16 <= end; i += 16) {
        int e0 = i + q8, e1 = i + 8 + q8;
        int s0 = col[e0], s1 = col[e1];
        uint2 u0 = bufld_u64(h2r, (s0 << 6) + clByte);
        uint2 u1 = bufld_u64(h2r, (s1 << 6) + clByte);
        float l0 = bufld_f32(asr, s0 << 2);
        float l1 = bufld_f32(asr, s1 << 2);
        A2SLOT(u0, l0) A2SLOT(u1, l1)
    }
    for (; i < end; i += 8) {
        int e = i + q8;
        if (e < end) {
            int s = col[e];
            uint2 u = bufld_u64(h2r, (s << 6) + clByte);
            float l = bufld_f32(asr, s << 2);
            A2SLOT(u, l)
        }
    }
    den += __shfl_xor(den, 8, 64);
    den += __shfl_xor(den, 16, 64);
    den += __shfl_xor(den, 32, 64);
    a0 += __shfl_xor(a0, 8, 64);  a0 += __shfl_xor(a0, 16, 64);  a0 += __shfl_xor(a0, 32, 64);
    a1 += __shfl_xor(a1, 8, 64);  a1 += __shfl_xor(a1, 16, 64);  a1 += __shfl_xor(a1, 32, 64);
    a2 += __shfl_xor(a2, 8, 64);  a2 += __shfl_xor(a2, 16, 64);  a2 += __shfl_xor(a2, 32, 64);
    a3 += __shfl_xor(a3, 8, 64);  a3 += __shfl_xor(a3, 16, 64);  a3 += __shfl_xor(a3, 32, 64);
    if (q8 == 0) {
        float4 bb = ((const float4*)b2)[cl];
        float4 o;
        o.x = a0 / den + bb.x;
        o.y = a1 / den + bb.y;
        o.z = a2 / den + bb.z;
        o.w = a3 / den + bb.w;
        ((float4*)out)[n * 8 + cl] = o;
    }
}

// ---------------- launch ----------------

extern "C" void kernel_launch(void* const* d_in, const int* in_sizes, int n_in,
                              void* d_out, int out_size, void* d_ws, size_t ws_size,
                              hipStream_t stream) {
    const float* x    = (const float*)d_in[0];
    const int*   ei   = (const int*)d_in[1];
    const float* W1   = (const float*)d_in[2];
    const float* a_s1 = (const float*)d_in[3];
    const float* a_d1 = (const float*)d_in[4];
    const float* b1   = (const float*)d_in[5];
    const float* W2   = (const float*)d_in[6];
    const float* a_s2 = (const float*)d_in[7];
    const float* a_d2 = (const float*)d_in[8];
    const float* b2   = (const float*)d_in[9];

    int N = in_sizes[0] / 128;
    int E = in_sizes[1] / 2;
    const int* srcA = ei;
    const int* dstA = ei + E;
    int Etot = E + N;

    char* ws = (char*)d_ws;
    size_t off = 0;
    auto alloc = [&](size_t bytes) {
        void* p = ws + off;
        off += (bytes + 255) & ~(size_t)255;
        return p;
    };
    unsigned* h1b   = (unsigned*)alloc((size_t)N * 128 * 2);
    unsigned* out1b = (unsigned*)alloc((size_t)N * 128 * 2);
    unsigned* h2b   = (unsigned*)alloc((size_t)N * 32 * 2);
    float* as1      = (float*)alloc((size_t)N * 4 * 4);
    float* ad1      = (float*)alloc((size_t)N * 4 * 4);
    float* as2      = (float*)alloc((size_t)N * 4);
    float* ad2      = (float*)alloc((size_t)N * 4);
    int*   rowptr   = (int*)alloc((size_t)(N + 1) * 4);
    int*   col      = (int*)alloc((size_t)Etot * 4);
    unsigned* pairs = (unsigned*)alloc((size_t)Etot * 4);
    unsigned short* W1T = (unsigned short*)alloc(128 * 128 * 2);
    unsigned short* W2T = (unsigned short*)alloc(32 * 128 * 2);

    int nbuckets = (N + 255) >> 8;                 // 391
    int nblk1 = (Etot + EPB - 1) / EPB;            // 208
    int M = nbuckets * nblk1;
    int*   partial = (int*)alloc((size_t)M * 4);
    int nbs = (M + 255) / 256;
    int*   psum    = (int*)alloc((size_t)1024 * 4);

    int gblocks = (N + 63) / 64;

    // wcvt || p1_hist
    hipLaunchKernelGGL(wcvt_hist_kernel, dim3(80 + nblk1), dim3(256), 0, stream,
                       W1, W2, W1T, W2T, dstA, E, N, nblk1, nbuckets, partial);
    // scan
    hipLaunchKernelGGL(gscan_bsum, dim3(nbs), dim3(256), 0, stream, partial, psum, M);
    hipLaunchKernelGGL(gscan_psum, dim3(1), dim3(1024), 0, stream, psum, nbs);
    hipLaunchKernelGGL(gscan_final, dim3(nbs), dim3(256), 0, stream, partial, psum, M);
    // scatter
    hipLaunchKernelGGL(p1_scatter, dim3(nblk1), dim3(256), 0, stream,
                       srcA, dstA, E, N, nblk1, nbuckets, partial, pairs);
    // p2 || gemm1
    hipLaunchKernelGGL(p2_gemm1_kernel, dim3(nbuckets + gblocks), dim3(256), 0, stream,
                       pairs, partial, nblk1, nbuckets, Etot, N, rowptr, col,
                       x, W1T, a_s1, a_d1, (uint4*)h1b, as1, ad1);

    // GAT layers
    hipLaunchKernelGGL(agg1_kernel, dim3((N + 3) / 4), dim3(256), 0, stream,
                       rowptr, col, h1b, as1, ad1, b1, out1b, N);
    hipLaunchKernelGGL(gemm2_kernel, dim3(gblocks), dim3(256), 0, stream,
                       (const uint4*)out1b, W2T, a_s2, a_d2, (uint4*)h2b, as2, ad2, N);
    hipLaunchKernelGGL(agg2_kernel, dim3((N + 3) / 4), dim3(256), 0, stream,
                       rowptr, col, h2b, as2, ad2, b2, (float*)d_out, N);
}